// Round 1
// baseline (1572.378 us; speedup 1.0000x reference)
//
#include <hip/hip_runtime.h>

#define NNODES 100000
#define NEDGES 1600000
#define HID    128
#define INDIM  64

// ============================ graph preprocessing ============================

__global__ __launch_bounds__(256) void hist_kernel(const int* __restrict__ ei, const float* __restrict__ ew,
                                                   unsigned* __restrict__ counts, float* __restrict__ wdeg) {
  int e = blockIdx.x * 256 + threadIdx.x;
  if (e >= NEDGES) return;
  int d = ei[NEDGES + e];
  atomicAdd(&counts[d], 1u);
  atomicAdd(&wdeg[d], ew[e]);
}

__global__ __launch_bounds__(256) void dinv_kernel(const float* __restrict__ wdeg, float* __restrict__ dinv) {
  int i = blockIdx.x * 256 + threadIdx.x;
  if (i < NNODES) dinv[i] = rsqrtf(wdeg[i] + 1.0f);
}

__global__ __launch_bounds__(256) void scan1_kernel(const unsigned* __restrict__ counts,
                                                    unsigned* __restrict__ part, unsigned* __restrict__ bsums) {
  __shared__ unsigned s[256];
  int i = blockIdx.x * 256 + threadIdx.x;
  unsigned v = (i < NNODES) ? counts[i] : 0u;
  s[threadIdx.x] = v;
  __syncthreads();
  for (int off = 1; off < 256; off <<= 1) {
    unsigned t = (threadIdx.x >= off) ? s[threadIdx.x - off] : 0u;
    __syncthreads();
    s[threadIdx.x] += t;
    __syncthreads();
  }
  if (i < NNODES) part[i] = s[threadIdx.x] - v;   // exclusive within block
  if (threadIdx.x == 255) bsums[blockIdx.x] = s[255];
}

__global__ void scan2_kernel(unsigned* __restrict__ bsums, unsigned* __restrict__ row_ofs, int nb) {
  __shared__ unsigned s[512];
  unsigned v = ((int)threadIdx.x < nb) ? bsums[threadIdx.x] : 0u;
  s[threadIdx.x] = v;
  __syncthreads();
  for (int off = 1; off < 512; off <<= 1) {
    unsigned t = (threadIdx.x >= off) ? s[threadIdx.x - off] : 0u;
    __syncthreads();
    s[threadIdx.x] += t;
    __syncthreads();
  }
  if ((int)threadIdx.x < nb) bsums[threadIdx.x] = s[threadIdx.x] - v; // exclusive block offsets
  if (threadIdx.x == 511) row_ofs[NNODES] = s[511];                   // total edge count
}

__global__ __launch_bounds__(256) void scan3_kernel(unsigned* __restrict__ row_ofs,
                                                    const unsigned* __restrict__ bsums,
                                                    unsigned* __restrict__ cursor) {
  int i = blockIdx.x * 256 + threadIdx.x;
  if (i < NNODES) {
    unsigned v = row_ofs[i] + bsums[blockIdx.x];
    row_ofs[i] = v;
    cursor[i] = v;
  }
}

__global__ __launch_bounds__(256) void scatter_kernel(const int* __restrict__ ei, const float* __restrict__ ew,
                                                      const float* __restrict__ dinv, unsigned* __restrict__ cursor,
                                                      unsigned* __restrict__ srcs, float* __restrict__ norms) {
  int e = blockIdx.x * 256 + threadIdx.x;
  if (e >= NEDGES) return;
  int s = ei[e];
  int d = ei[NEDGES + e];
  unsigned pos = atomicAdd(&cursor[d], 1u);
  srcs[pos]  = (unsigned)s;
  norms[pos] = ew[e] * dinv[s] * dinv[d];
}

// ============================ GEMM (fp32 vector) ============================
// out[N,128] = f(A)[N,K] @ W[K,128], f = BN(scale,shift)+ReLU if BN else identity.

template <int K, bool BN>
__global__ __launch_bounds__(256) void gemm_kernel(const float* __restrict__ A, const float* __restrict__ W,
                                                   const float* __restrict__ ss, float* __restrict__ out) {
  __shared__ float sA[64][33];     // +1 pad: conflict-free column reads
  __shared__ float sW[32][128];
  __shared__ float sScale[128];
  __shared__ float sShift[128];
  const int tid = threadIdx.x;
  if (BN && tid < K) { sScale[tid] = ss[tid]; sShift[tid] = ss[128 + tid]; }
  const int row0 = blockIdx.x * 64;
  float acc[4][8] = {};
  const int r0 = (tid >> 4) * 4;      // 16 row-groups * 4 rows = 64
  const int c0 = (tid & 15) * 8;      // 16 col-groups * 8 cols = 128
  const int lr = tid >> 3;            // A load: 32 rows per pass
  const int lc = (tid & 7) * 4;
  const int wr = tid >> 5;            // W load: 8 rows per pass
  const int wc = (tid & 31) * 4;

  for (int kk = 0; kk < K; kk += 32) {
    __syncthreads();
#pragma unroll
    for (int rep = 0; rep < 2; rep++) {
      int row = lr + rep * 32;
      int grow = row0 + row;
      float4 v = make_float4(0.f, 0.f, 0.f, 0.f);
      if (grow < NNODES) v = *reinterpret_cast<const float4*>(&A[(size_t)grow * K + kk + lc]);
      if (BN) {
        int cb = kk + lc;
        v.x = fmaxf(fmaf(v.x, sScale[cb + 0], sShift[cb + 0]), 0.f);
        v.y = fmaxf(fmaf(v.y, sScale[cb + 1], sShift[cb + 1]), 0.f);
        v.z = fmaxf(fmaf(v.z, sScale[cb + 2], sShift[cb + 2]), 0.f);
        v.w = fmaxf(fmaf(v.w, sScale[cb + 3], sShift[cb + 3]), 0.f);
      }
      sA[row][lc + 0] = v.x; sA[row][lc + 1] = v.y; sA[row][lc + 2] = v.z; sA[row][lc + 3] = v.w;
    }
#pragma unroll
    for (int rep = 0; rep < 4; rep++) {
      int row = wr + rep * 8;
      float4 v = *reinterpret_cast<const float4*>(&W[(size_t)(kk + row) * HID + wc]);
      *reinterpret_cast<float4*>(&sW[row][wc]) = v;
    }
    __syncthreads();
#pragma unroll
    for (int k = 0; k < 32; k++) {
      float a0 = sA[r0 + 0][k], a1 = sA[r0 + 1][k], a2 = sA[r0 + 2][k], a3 = sA[r0 + 3][k];
      float w[8];
      *reinterpret_cast<float4*>(&w[0]) = *reinterpret_cast<const float4*>(&sW[k][c0]);
      *reinterpret_cast<float4*>(&w[4]) = *reinterpret_cast<const float4*>(&sW[k][c0 + 4]);
#pragma unroll
      for (int j = 0; j < 8; j++) {
        acc[0][j] = fmaf(a0, w[j], acc[0][j]);
        acc[1][j] = fmaf(a1, w[j], acc[1][j]);
        acc[2][j] = fmaf(a2, w[j], acc[2][j]);
        acc[3][j] = fmaf(a3, w[j], acc[3][j]);
      }
    }
  }
#pragma unroll
  for (int i = 0; i < 4; i++) {
    int grow = row0 + r0 + i;
    if (grow < NNODES) {
      float4 o0 = make_float4(acc[i][0], acc[i][1], acc[i][2], acc[i][3]);
      float4 o1 = make_float4(acc[i][4], acc[i][5], acc[i][6], acc[i][7]);
      *reinterpret_cast<float4*>(&out[(size_t)grow * HID + c0])     = o0;
      *reinterpret_cast<float4*>(&out[(size_t)grow * HID + c0 + 4]) = o1;
    }
  }
}

// ============================ aggregation (CSR gather) ============================

__global__ __launch_bounds__(128) void agg_kernel(const float* __restrict__ hw, const unsigned* __restrict__ row_ofs,
                                                  const unsigned* __restrict__ srcs, const float* __restrict__ norms,
                                                  const float* __restrict__ dinv, const float* __restrict__ bias,
                                                  float* __restrict__ out) {
  const int node = blockIdx.x;
  const int c = threadIdx.x;
  const unsigned ro = row_ofs[node], re = row_ofs[node + 1];
  const float di = dinv[node];
  float acc = hw[(size_t)node * HID + c] * (di * di);   // self-loop term
  for (unsigned e = ro; e < re; ++e) {
    acc = fmaf(hw[(size_t)srcs[e] * HID + c], norms[e], acc);
  }
  out[(size_t)node * HID + c] = acc + bias[c];
}

// ============================ BatchNorm stats ============================

__global__ __launch_bounds__(256) void stats_kernel(const float* __restrict__ h, float* __restrict__ stats) {
  float sum = 0.f, ssq = 0.f;
  const size_t total = (size_t)NNODES * HID;
  for (size_t i = (size_t)blockIdx.x * 256 + threadIdx.x; i < total; i += (size_t)gridDim.x * 256) {
    float v = h[i];
    sum += v; ssq += v * v;
  }
  __shared__ float s1[256], s2[256];
  s1[threadIdx.x] = sum; s2[threadIdx.x] = ssq;
  __syncthreads();
  if (threadIdx.x < 128) {
    int col = threadIdx.x;   // (blk*256+tid) % 128 == tid % 128 since strides are multiples of 128
    atomicAdd(&stats[col],       s1[threadIdx.x] + s1[threadIdx.x + 128]);
    atomicAdd(&stats[128 + col], s2[threadIdx.x] + s2[threadIdx.x + 128]);
  }
}

__global__ void finalize_kernel(const float* __restrict__ stats, const float* __restrict__ gamma,
                                const float* __restrict__ beta, float* __restrict__ ss, float inv_n) {
  int c = threadIdx.x;  // 128 threads
  float mu  = stats[c] * inv_n;
  float var = stats[128 + c] * inv_n - mu * mu;
  float scale = gamma[c] * rsqrtf(var + 1e-5f);
  ss[c]       = scale;
  ss[128 + c] = fmaf(-mu, scale, beta[c]);
}

__global__ __launch_bounds__(256) void normout_kernel(const float* __restrict__ h, const float* __restrict__ ss,
                                                      float* __restrict__ out) {
  size_t i = (size_t)blockIdx.x * 256 + threadIdx.x;
  if (i >= (size_t)NNODES * HID / 4) return;
  float4 v = reinterpret_cast<const float4*>(h)[i];
  int c = ((int)i & 31) * 4;
  v.x = fmaf(v.x, ss[c + 0], ss[128 + c + 0]);
  v.y = fmaf(v.y, ss[c + 1], ss[128 + c + 1]);
  v.z = fmaf(v.z, ss[c + 2], ss[128 + c + 2]);
  v.w = fmaf(v.w, ss[c + 3], ss[128 + c + 3]);
  reinterpret_cast<float4*>(out)[i] = v;
}

// ============================ launch ============================

extern "C" void kernel_launch(void* const* d_in, const int* in_sizes, int n_in,
                              void* d_out, int out_size, void* d_ws, size_t ws_size,
                              hipStream_t stream) {
  const float* x     = (const float*)d_in[0];
  const int*   ei    = (const int*)d_in[1];
  const float* ew    = (const float*)d_in[2];
  const float* W_in  = (const float*)d_in[3];
  const float* b_in  = (const float*)d_in[4];
  const float* W_mid = (const float*)d_in[5];
  const float* b_mid = (const float*)d_in[6];
  const float* W_out = (const float*)d_in[7];
  const float* b_out = (const float*)d_in[8];
  const float* gamma = (const float*)d_in[9];
  const float* beta  = (const float*)d_in[10];

  char* p = (char*)d_ws;
  auto alloc = [&](size_t bytes) -> char* {
    char* r = p;
    p += (bytes + 255) & ~(size_t)255;
    return r;
  };
  float*    wdeg    = (float*)alloc((size_t)NNODES * 4);
  unsigned* counts  = (unsigned*)alloc((size_t)NNODES * 4);
  float*    stats   = (float*)alloc(5 * 256 * 4);
  size_t zbytes = (size_t)(p - (char*)d_ws);          // wdeg+counts+stats get zeroed
  float*    dinv    = (float*)alloc((size_t)NNODES * 4);
  unsigned* row_ofs = (unsigned*)alloc((size_t)(NNODES + 1) * 4);
  unsigned* cursor  = (unsigned*)alloc((size_t)NNODES * 4);
  float*    ss      = (float*)alloc(5 * 256 * 4);
  unsigned* bsums   = (unsigned*)alloc(512 * 4);
  unsigned* srcs    = (unsigned*)alloc((size_t)NEDGES * 4);
  float*    norms   = (float*)alloc((size_t)NEDGES * 4);
  float*    hA      = (float*)alloc((size_t)NNODES * HID * 4);
  float*    hB      = (float*)alloc((size_t)NNODES * HID * 4);
  float*    hw      = (float*)d_out;                  // reuse d_out as GEMM-output scratch

  hipMemsetAsync(d_ws, 0, zbytes, stream);

  const int eb = (NEDGES + 255) / 256;
  const int nb = (NNODES + 255) / 256;
  hist_kernel<<<eb, 256, 0, stream>>>(ei, ew, counts, wdeg);
  dinv_kernel<<<nb, 256, 0, stream>>>(wdeg, dinv);
  scan1_kernel<<<nb, 256, 0, stream>>>(counts, row_ofs, bsums);
  scan2_kernel<<<1, 512, 0, stream>>>(bsums, row_ofs, nb);
  scan3_kernel<<<nb, 256, 0, stream>>>(row_ofs, bsums, cursor);
  scatter_kernel<<<eb, 256, 0, stream>>>(ei, ew, dinv, cursor, srcs, norms);

  const int gb = (NNODES + 63) / 64;
  const float inv_n = 1.0f / NNODES;

  // layer 0: raw x (K=64), no BN on input
  gemm_kernel<INDIM, false><<<gb, 256, 0, stream>>>(x, W_in, nullptr, hw);
  agg_kernel<<<NNODES, 128, 0, stream>>>(hw, row_ofs, srcs, norms, dinv, b_in, hA);
  stats_kernel<<<512, 256, 0, stream>>>(hA, stats);
  finalize_kernel<<<1, 128, 0, stream>>>(stats, gamma, beta, ss, inv_n);

  const float* hin = hA;
  float* hout = hB;
  for (int l = 1; l <= 4; l++) {
    const float* W = (l <= 3) ? (W_mid + (size_t)(l - 1) * HID * HID) : W_out;
    const float* b = (l <= 3) ? (b_mid + (size_t)(l - 1) * HID) : b_out;
    gemm_kernel<HID, true><<<gb, 256, 0, stream>>>(hin, W, ss + (size_t)(l - 1) * 256, hw);
    agg_kernel<<<NNODES, 128, 0, stream>>>(hw, row_ofs, srcs, norms, dinv, b, hout);
    stats_kernel<<<512, 256, 0, stream>>>(hout, stats + (size_t)l * 256);
    finalize_kernel<<<1, 128, 0, stream>>>(stats + (size_t)l * 256, gamma + (size_t)l * HID,
                                           beta + (size_t)l * HID, ss + (size_t)l * 256, inv_n);
    const float* t = hout; hout = (float*)hin; hin = t;
  }
  // hin == layer-4 raw output; apply final BN (no ReLU) into d_out
  normout_kernel<<<((NNODES * HID / 4) + 255) / 256, 256, 0, stream>>>(hin, ss + 4 * 256, (float*)d_out);
}

// Round 2
// 1513.938 us; speedup vs baseline: 1.0386x; 1.0386x over previous
//
#include <hip/hip_runtime.h>

#define NNODES 100000
#define NEDGES 1600000
#define HID    128
#define INDIM  64

// ============================ graph preprocessing ============================

__global__ __launch_bounds__(256) void hist_kernel(const int* __restrict__ ei, const float* __restrict__ ew,
                                                   unsigned* __restrict__ counts, float* __restrict__ wdeg) {
  int e = blockIdx.x * 256 + threadIdx.x;
  if (e >= NEDGES) return;
  int d = ei[NEDGES + e];
  atomicAdd(&counts[d], 1u);
  atomicAdd(&wdeg[d], ew[e]);
}

__global__ __launch_bounds__(256) void dinv_kernel(const float* __restrict__ wdeg, float* __restrict__ dinv) {
  int i = blockIdx.x * 256 + threadIdx.x;
  if (i < NNODES) dinv[i] = rsqrtf(wdeg[i] + 1.0f);
}

__global__ __launch_bounds__(256) void scan1_kernel(const unsigned* __restrict__ counts,
                                                    unsigned* __restrict__ part, unsigned* __restrict__ bsums) {
  __shared__ unsigned s[256];
  int i = blockIdx.x * 256 + threadIdx.x;
  unsigned v = (i < NNODES) ? counts[i] : 0u;
  s[threadIdx.x] = v;
  __syncthreads();
  for (int off = 1; off < 256; off <<= 1) {
    unsigned t = (threadIdx.x >= off) ? s[threadIdx.x - off] : 0u;
    __syncthreads();
    s[threadIdx.x] += t;
    __syncthreads();
  }
  if (i < NNODES) part[i] = s[threadIdx.x] - v;   // exclusive within block
  if (threadIdx.x == 255) bsums[blockIdx.x] = s[255];
}

__global__ void scan2_kernel(unsigned* __restrict__ bsums, unsigned* __restrict__ row_ofs, int nb) {
  __shared__ unsigned s[512];
  unsigned v = ((int)threadIdx.x < nb) ? bsums[threadIdx.x] : 0u;
  s[threadIdx.x] = v;
  __syncthreads();
  for (int off = 1; off < 512; off <<= 1) {
    unsigned t = (threadIdx.x >= off) ? s[threadIdx.x - off] : 0u;
    __syncthreads();
    s[threadIdx.x] += t;
    __syncthreads();
  }
  if ((int)threadIdx.x < nb) bsums[threadIdx.x] = s[threadIdx.x] - v; // exclusive block offsets
  if (threadIdx.x == 511) row_ofs[NNODES] = s[511];                   // total edge count
}

__global__ __launch_bounds__(256) void scan3_kernel(unsigned* __restrict__ row_ofs,
                                                    const unsigned* __restrict__ bsums,
                                                    unsigned* __restrict__ cursor) {
  int i = blockIdx.x * 256 + threadIdx.x;
  if (i < NNODES) {
    unsigned v = row_ofs[i] + bsums[blockIdx.x];
    row_ofs[i] = v;
    cursor[i] = v;
  }
}

__global__ __launch_bounds__(256) void scatter_kernel(const int* __restrict__ ei, const float* __restrict__ ew,
                                                      const float* __restrict__ dinv, unsigned* __restrict__ cursor,
                                                      unsigned* __restrict__ srcs, float* __restrict__ norms) {
  int e = blockIdx.x * 256 + threadIdx.x;
  if (e >= NEDGES) return;
  int s = ei[e];
  int d = ei[NEDGES + e];
  unsigned pos = atomicAdd(&cursor[d], 1u);
  srcs[pos]  = (unsigned)s;
  norms[pos] = ew[e] * dinv[s] * dinv[d];
}

// ============================ GEMM (fp32 vector, bf16 output) ============================
// out[N,128](bf16) = f(A)[N,K] @ W[K,128], f = BN(scale,shift)+ReLU if BN else identity.

__device__ __forceinline__ unsigned pack_bf16x2(float a, float b) {
  unsigned ua = __float_as_uint(a), ub = __float_as_uint(b);
  ua = (ua + 0x7fffu + ((ua >> 16) & 1u)) >> 16;
  ub = (ub + 0x7fffu + ((ub >> 16) & 1u)) >> 16;
  return ua | (ub << 16);
}

template <int K, bool BN>
__global__ __launch_bounds__(256) void gemm_kernel(const float* __restrict__ A, const float* __restrict__ W,
                                                   const float* __restrict__ ss, unsigned* __restrict__ out) {
  __shared__ float sA[64][33];     // +1 pad: conflict-free column reads
  __shared__ float sW[32][128];
  __shared__ float sScale[128];
  __shared__ float sShift[128];
  const int tid = threadIdx.x;
  if (BN && tid < K) { sScale[tid] = ss[tid]; sShift[tid] = ss[128 + tid]; }
  const int row0 = blockIdx.x * 64;
  float acc[4][8] = {};
  const int r0 = (tid >> 4) * 4;      // 16 row-groups * 4 rows = 64
  const int c0 = (tid & 15) * 8;      // 16 col-groups * 8 cols = 128
  const int lr = tid >> 3;            // A load: 32 rows per pass
  const int lc = (tid & 7) * 4;
  const int wr = tid >> 5;            // W load: 8 rows per pass
  const int wc = (tid & 31) * 4;

  for (int kk = 0; kk < K; kk += 32) {
    __syncthreads();
#pragma unroll
    for (int rep = 0; rep < 2; rep++) {
      int row = lr + rep * 32;
      int grow = row0 + row;
      float4 v = make_float4(0.f, 0.f, 0.f, 0.f);
      if (grow < NNODES) v = *reinterpret_cast<const float4*>(&A[(size_t)grow * K + kk + lc]);
      if (BN) {
        int cb = kk + lc;
        v.x = fmaxf(fmaf(v.x, sScale[cb + 0], sShift[cb + 0]), 0.f);
        v.y = fmaxf(fmaf(v.y, sScale[cb + 1], sShift[cb + 1]), 0.f);
        v.z = fmaxf(fmaf(v.z, sScale[cb + 2], sShift[cb + 2]), 0.f);
        v.w = fmaxf(fmaf(v.w, sScale[cb + 3], sShift[cb + 3]), 0.f);
      }
      sA[row][lc + 0] = v.x; sA[row][lc + 1] = v.y; sA[row][lc + 2] = v.z; sA[row][lc + 3] = v.w;
    }
#pragma unroll
    for (int rep = 0; rep < 4; rep++) {
      int row = wr + rep * 8;
      float4 v = *reinterpret_cast<const float4*>(&W[(size_t)(kk + row) * HID + wc]);
      *reinterpret_cast<float4*>(&sW[row][wc]) = v;
    }
    __syncthreads();
#pragma unroll
    for (int k = 0; k < 32; k++) {
      float a0 = sA[r0 + 0][k], a1 = sA[r0 + 1][k], a2 = sA[r0 + 2][k], a3 = sA[r0 + 3][k];
      float w[8];
      *reinterpret_cast<float4*>(&w[0]) = *reinterpret_cast<const float4*>(&sW[k][c0]);
      *reinterpret_cast<float4*>(&w[4]) = *reinterpret_cast<const float4*>(&sW[k][c0 + 4]);
#pragma unroll
      for (int j = 0; j < 8; j++) {
        acc[0][j] = fmaf(a0, w[j], acc[0][j]);
        acc[1][j] = fmaf(a1, w[j], acc[1][j]);
        acc[2][j] = fmaf(a2, w[j], acc[2][j]);
        acc[3][j] = fmaf(a3, w[j], acc[3][j]);
      }
    }
  }
  // epilogue: pack to bf16, 8 cols -> uint4 (16B) per row
#pragma unroll
  for (int i = 0; i < 4; i++) {
    int grow = row0 + r0 + i;
    if (grow < NNODES) {
      uint4 o;
      o.x = pack_bf16x2(acc[i][0], acc[i][1]);
      o.y = pack_bf16x2(acc[i][2], acc[i][3]);
      o.z = pack_bf16x2(acc[i][4], acc[i][5]);
      o.w = pack_bf16x2(acc[i][6], acc[i][7]);
      *reinterpret_cast<uint4*>(&out[(size_t)grow * (HID / 2) + (c0 / 2)]) = o;
    }
  }
}

// ============================ aggregation (CSR gather, bf16 rows) ============================
// One 64-lane wave per node; lane holds 2 adjacent columns (one bf16x2 word).

__device__ __forceinline__ float bf16lo(unsigned u) { return __uint_as_float(u << 16); }
__device__ __forceinline__ float bf16hi(unsigned u) { return __uint_as_float(u & 0xffff0000u); }

__global__ __launch_bounds__(256) void agg_kernel(const unsigned* __restrict__ hwb,
                                                  const unsigned* __restrict__ row_ofs,
                                                  const unsigned* __restrict__ srcs, const float* __restrict__ norms,
                                                  const float* __restrict__ dinv, const float* __restrict__ bias,
                                                  float* __restrict__ out) {
  const int node = (blockIdx.x * 256 + threadIdx.x) >> 6;
  const int lane = threadIdx.x & 63;
  if (node >= NNODES) return;
  const unsigned ro = row_ofs[node], re = row_ofs[node + 1];
  const float di = dinv[node];
  const float w0 = di * di;
  unsigned u = hwb[(size_t)node * 64 + lane];          // self-loop row
  float acc0 = bf16lo(u) * w0;
  float acc1 = bf16hi(u) * w0;
  for (unsigned e = ro; e < re; ++e) {
    const unsigned s = srcs[e];
    const float w = norms[e];
    const unsigned v = hwb[(size_t)s * 64 + lane];
    acc0 = fmaf(bf16lo(v), w, acc0);
    acc1 = fmaf(bf16hi(v), w, acc1);
  }
  float2 o = make_float2(acc0 + bias[2 * lane], acc1 + bias[2 * lane + 1]);
  *reinterpret_cast<float2*>(&out[(size_t)node * HID + 2 * lane]) = o;
}

// ============================ BatchNorm stats ============================

__global__ __launch_bounds__(256) void stats_kernel(const float* __restrict__ h, float* __restrict__ stats) {
  float sum = 0.f, ssq = 0.f;
  const size_t total = (size_t)NNODES * HID;
  for (size_t i = (size_t)blockIdx.x * 256 + threadIdx.x; i < total; i += (size_t)gridDim.x * 256) {
    float v = h[i];
    sum += v; ssq += v * v;
  }
  __shared__ float s1[256], s2[256];
  s1[threadIdx.x] = sum; s2[threadIdx.x] = ssq;
  __syncthreads();
  if (threadIdx.x < 128) {
    int col = threadIdx.x;   // (blk*256+tid) % 128 == tid % 128 since strides are multiples of 128
    atomicAdd(&stats[col],       s1[threadIdx.x] + s1[threadIdx.x + 128]);
    atomicAdd(&stats[128 + col], s2[threadIdx.x] + s2[threadIdx.x + 128]);
  }
}

__global__ void finalize_kernel(const float* __restrict__ stats, const float* __restrict__ gamma,
                                const float* __restrict__ beta, float* __restrict__ ss, float inv_n) {
  int c = threadIdx.x;  // 128 threads
  float mu  = stats[c] * inv_n;
  float var = stats[128 + c] * inv_n - mu * mu;
  float scale = gamma[c] * rsqrtf(var + 1e-5f);
  ss[c]       = scale;
  ss[128 + c] = fmaf(-mu, scale, beta[c]);
}

__global__ __launch_bounds__(256) void normout_kernel(const float* __restrict__ h, const float* __restrict__ ss,
                                                      float* __restrict__ out) {
  size_t i = (size_t)blockIdx.x * 256 + threadIdx.x;
  if (i >= (size_t)NNODES * HID / 4) return;
  float4 v = reinterpret_cast<const float4*>(h)[i];
  int c = ((int)i & 31) * 4;
  v.x = fmaf(v.x, ss[c + 0], ss[128 + c + 0]);
  v.y = fmaf(v.y, ss[c + 1], ss[128 + c + 1]);
  v.z = fmaf(v.z, ss[c + 2], ss[128 + c + 2]);
  v.w = fmaf(v.w, ss[c + 3], ss[128 + c + 3]);
  reinterpret_cast<float4*>(out)[i] = v;
}

// ============================ launch ============================

extern "C" void kernel_launch(void* const* d_in, const int* in_sizes, int n_in,
                              void* d_out, int out_size, void* d_ws, size_t ws_size,
                              hipStream_t stream) {
  const float* x     = (const float*)d_in[0];
  const int*   ei    = (const int*)d_in[1];
  const float* ew    = (const float*)d_in[2];
  const float* W_in  = (const float*)d_in[3];
  const float* b_in  = (const float*)d_in[4];
  const float* W_mid = (const float*)d_in[5];
  const float* b_mid = (const float*)d_in[6];
  const float* W_out = (const float*)d_in[7];
  const float* b_out = (const float*)d_in[8];
  const float* gamma = (const float*)d_in[9];
  const float* beta  = (const float*)d_in[10];

  char* p = (char*)d_ws;
  auto alloc = [&](size_t bytes) -> char* {
    char* r = p;
    p += (bytes + 255) & ~(size_t)255;
    return r;
  };
  float*    wdeg    = (float*)alloc((size_t)NNODES * 4);
  unsigned* counts  = (unsigned*)alloc((size_t)NNODES * 4);
  float*    stats   = (float*)alloc(5 * 256 * 4);
  size_t zbytes = (size_t)(p - (char*)d_ws);          // wdeg+counts+stats get zeroed
  float*    dinv    = (float*)alloc((size_t)NNODES * 4);
  unsigned* row_ofs = (unsigned*)alloc((size_t)(NNODES + 1) * 4);
  unsigned* cursor  = (unsigned*)alloc((size_t)NNODES * 4);
  float*    ss      = (float*)alloc(5 * 256 * 4);
  unsigned* bsums   = (unsigned*)alloc(512 * 4);
  unsigned* srcs    = (unsigned*)alloc((size_t)NEDGES * 4);
  float*    norms   = (float*)alloc((size_t)NEDGES * 4);
  float*    hA      = (float*)alloc((size_t)NNODES * HID * 4);
  float*    hB      = (float*)alloc((size_t)NNODES * HID * 4);
  unsigned* hw      = (unsigned*)d_out;               // reuse d_out as bf16x2 GEMM-output scratch (25.6MB of 51.2MB)

  hipMemsetAsync(d_ws, 0, zbytes, stream);

  const int eb = (NEDGES + 255) / 256;
  const int nb = (NNODES + 255) / 256;
  hist_kernel<<<eb, 256, 0, stream>>>(ei, ew, counts, wdeg);
  dinv_kernel<<<nb, 256, 0, stream>>>(wdeg, dinv);
  scan1_kernel<<<nb, 256, 0, stream>>>(counts, row_ofs, bsums);
  scan2_kernel<<<1, 512, 0, stream>>>(bsums, row_ofs, nb);
  scan3_kernel<<<nb, 256, 0, stream>>>(row_ofs, bsums, cursor);
  scatter_kernel<<<eb, 256, 0, stream>>>(ei, ew, dinv, cursor, srcs, norms);

  const int gb = (NNODES + 63) / 64;
  const int ab = (NNODES * 64 + 255) / 256;
  const float inv_n = 1.0f / NNODES;

  // layer 0: raw x (K=64), no BN on input
  gemm_kernel<INDIM, false><<<gb, 256, 0, stream>>>(x, W_in, nullptr, hw);
  agg_kernel<<<ab, 256, 0, stream>>>(hw, row_ofs, srcs, norms, dinv, b_in, hA);
  stats_kernel<<<512, 256, 0, stream>>>(hA, stats);
  finalize_kernel<<<1, 128, 0, stream>>>(stats, gamma, beta, ss, inv_n);

  const float* hin = hA;
  float* hout = hB;
  for (int l = 1; l <= 4; l++) {
    const float* W = (l <= 3) ? (W_mid + (size_t)(l - 1) * HID * HID) : W_out;
    const float* b = (l <= 3) ? (b_mid + (size_t)(l - 1) * HID) : b_out;
    gemm_kernel<HID, true><<<gb, 256, 0, stream>>>(hin, W, ss + (size_t)(l - 1) * 256, hw);
    agg_kernel<<<ab, 256, 0, stream>>>(hw, row_ofs, srcs, norms, dinv, b, hout);
    stats_kernel<<<512, 256, 0, stream>>>(hout, stats + (size_t)l * 256);
    finalize_kernel<<<1, 128, 0, stream>>>(stats + (size_t)l * 256, gamma + (size_t)l * HID,
                                           beta + (size_t)l * HID, ss + (size_t)l * 256, inv_n);
    const float* t = hout; hout = (float*)hin; hin = t;
  }
  // hin == layer-4 raw output; apply final BN (no ReLU) into d_out
  normout_kernel<<<((NNODES * HID / 4) + 255) / 256, 256, 0, stream>>>(hin, ss + 4 * 256, (float*)d_out);
}

// Round 3
// 1073.794 us; speedup vs baseline: 1.4643x; 1.4099x over previous
//
#include <hip/hip_runtime.h>

#define NNODES 100000
#define NEDGES 1600000
#define HID    128
#define INDIM  64

// ============================ graph preprocessing ============================

__global__ __launch_bounds__(256) void hist_kernel(const int* __restrict__ ei, const float* __restrict__ ew,
                                                   unsigned* __restrict__ counts, float* __restrict__ wdeg) {
  int e = blockIdx.x * 256 + threadIdx.x;
  if (e >= NEDGES) return;
  int d = ei[NEDGES + e];
  atomicAdd(&counts[d], 1u);
  atomicAdd(&wdeg[d], ew[e]);
}

__global__ __launch_bounds__(256) void dinv_kernel(const float* __restrict__ wdeg, float* __restrict__ dinv) {
  int i = blockIdx.x * 256 + threadIdx.x;
  if (i < NNODES) dinv[i] = rsqrtf(wdeg[i] + 1.0f);
}

__global__ __launch_bounds__(256) void scan1_kernel(const unsigned* __restrict__ counts,
                                                    unsigned* __restrict__ part, unsigned* __restrict__ bsums) {
  __shared__ unsigned s[256];
  int i = blockIdx.x * 256 + threadIdx.x;
  unsigned v = (i < NNODES) ? counts[i] : 0u;
  s[threadIdx.x] = v;
  __syncthreads();
  for (int off = 1; off < 256; off <<= 1) {
    unsigned t = (threadIdx.x >= off) ? s[threadIdx.x - off] : 0u;
    __syncthreads();
    s[threadIdx.x] += t;
    __syncthreads();
  }
  if (i < NNODES) part[i] = s[threadIdx.x] - v;   // exclusive within block
  if (threadIdx.x == 255) bsums[blockIdx.x] = s[255];
}

__global__ void scan2_kernel(unsigned* __restrict__ bsums, unsigned* __restrict__ row_ofs, int nb) {
  __shared__ unsigned s[512];
  unsigned v = ((int)threadIdx.x < nb) ? bsums[threadIdx.x] : 0u;
  s[threadIdx.x] = v;
  __syncthreads();
  for (int off = 1; off < 512; off <<= 1) {
    unsigned t = (threadIdx.x >= off) ? s[threadIdx.x - off] : 0u;
    __syncthreads();
    s[threadIdx.x] += t;
    __syncthreads();
  }
  if ((int)threadIdx.x < nb) bsums[threadIdx.x] = s[threadIdx.x] - v; // exclusive block offsets
  if (threadIdx.x == 511) row_ofs[NNODES] = s[511];                   // total edge count
}

__global__ __launch_bounds__(256) void scan3_kernel(unsigned* __restrict__ row_ofs,
                                                    const unsigned* __restrict__ bsums,
                                                    unsigned* __restrict__ cursor) {
  int i = blockIdx.x * 256 + threadIdx.x;
  if (i < NNODES) {
    unsigned v = row_ofs[i] + bsums[blockIdx.x];
    row_ofs[i] = v;
    cursor[i] = v;
  }
}

// edges[pos] = {src, float_bits(norm)} — one 8B record per edge, interleaved for the agg gather.
__global__ __launch_bounds__(256) void scatter_kernel(const int* __restrict__ ei, const float* __restrict__ ew,
                                                      const float* __restrict__ dinv, unsigned* __restrict__ cursor,
                                                      uint2* __restrict__ edges) {
  int e = blockIdx.x * 256 + threadIdx.x;
  if (e >= NEDGES) return;
  int s = ei[e];
  int d = ei[NEDGES + e];
  unsigned pos = atomicAdd(&cursor[d], 1u);
  uint2 rec;
  rec.x = (unsigned)s;
  rec.y = __float_as_uint(ew[e] * dinv[s] * dinv[d]);
  edges[pos] = rec;
}

// ============================ GEMM (fp32 vector, bf16 output) ============================
// out[N,128](bf16) = f(A)[N,K] @ W[K,128], f = BN(scale,shift)+ReLU if BN else identity.

__device__ __forceinline__ unsigned pack_bf16x2(float a, float b) {
  unsigned ua = __float_as_uint(a), ub = __float_as_uint(b);
  ua = (ua + 0x7fffu + ((ua >> 16) & 1u)) >> 16;
  ub = (ub + 0x7fffu + ((ub >> 16) & 1u)) >> 16;
  return ua | (ub << 16);
}

template <int K, bool BN>
__global__ __launch_bounds__(256) void gemm_kernel(const float* __restrict__ A, const float* __restrict__ W,
                                                   const float* __restrict__ ss, unsigned* __restrict__ out) {
  __shared__ float sA[64][33];     // +1 pad: conflict-free column reads
  __shared__ float sW[32][128];
  __shared__ float sScale[128];
  __shared__ float sShift[128];
  const int tid = threadIdx.x;
  if (BN && tid < K) { sScale[tid] = ss[tid]; sShift[tid] = ss[128 + tid]; }
  const int row0 = blockIdx.x * 64;
  float acc[4][8] = {};
  const int r0 = (tid >> 4) * 4;      // 16 row-groups * 4 rows = 64
  const int c0 = (tid & 15) * 8;      // 16 col-groups * 8 cols = 128
  const int lr = tid >> 3;            // A load: 32 rows per pass
  const int lc = (tid & 7) * 4;
  const int wr = tid >> 5;            // W load: 8 rows per pass
  const int wc = (tid & 31) * 4;

  for (int kk = 0; kk < K; kk += 32) {
    __syncthreads();
#pragma unroll
    for (int rep = 0; rep < 2; rep++) {
      int row = lr + rep * 32;
      int grow = row0 + row;
      float4 v = make_float4(0.f, 0.f, 0.f, 0.f);
      if (grow < NNODES) v = *reinterpret_cast<const float4*>(&A[(size_t)grow * K + kk + lc]);
      if (BN) {
        int cb = kk + lc;
        v.x = fmaxf(fmaf(v.x, sScale[cb + 0], sShift[cb + 0]), 0.f);
        v.y = fmaxf(fmaf(v.y, sScale[cb + 1], sShift[cb + 1]), 0.f);
        v.z = fmaxf(fmaf(v.z, sScale[cb + 2], sShift[cb + 2]), 0.f);
        v.w = fmaxf(fmaf(v.w, sScale[cb + 3], sShift[cb + 3]), 0.f);
      }
      sA[row][lc + 0] = v.x; sA[row][lc + 1] = v.y; sA[row][lc + 2] = v.z; sA[row][lc + 3] = v.w;
    }
#pragma unroll
    for (int rep = 0; rep < 4; rep++) {
      int row = wr + rep * 8;
      float4 v = *reinterpret_cast<const float4*>(&W[(size_t)(kk + row) * HID + wc]);
      *reinterpret_cast<float4*>(&sW[row][wc]) = v;
    }
    __syncthreads();
#pragma unroll
    for (int k = 0; k < 32; k++) {
      float a0 = sA[r0 + 0][k], a1 = sA[r0 + 1][k], a2 = sA[r0 + 2][k], a3 = sA[r0 + 3][k];
      float w[8];
      *reinterpret_cast<float4*>(&w[0]) = *reinterpret_cast<const float4*>(&sW[k][c0]);
      *reinterpret_cast<float4*>(&w[4]) = *reinterpret_cast<const float4*>(&sW[k][c0 + 4]);
#pragma unroll
      for (int j = 0; j < 8; j++) {
        acc[0][j] = fmaf(a0, w[j], acc[0][j]);
        acc[1][j] = fmaf(a1, w[j], acc[1][j]);
        acc[2][j] = fmaf(a2, w[j], acc[2][j]);
        acc[3][j] = fmaf(a3, w[j], acc[3][j]);
      }
    }
  }
  // epilogue: pack to bf16, 8 cols -> uint4 (16B) per row
#pragma unroll
  for (int i = 0; i < 4; i++) {
    int grow = row0 + r0 + i;
    if (grow < NNODES) {
      uint4 o;
      o.x = pack_bf16x2(acc[i][0], acc[i][1]);
      o.y = pack_bf16x2(acc[i][2], acc[i][3]);
      o.z = pack_bf16x2(acc[i][4], acc[i][5]);
      o.w = pack_bf16x2(acc[i][6], acc[i][7]);
      *reinterpret_cast<uint4*>(&out[(size_t)grow * (HID / 2) + (c0 / 2)]) = o;
    }
  }
}

// ============================ aggregation (CSR gather, bf16 rows, 4-deep MLP) ============================
// One 64-lane wave per node; lane holds 2 adjacent columns (one bf16x2 word).
// Edge loop unrolled x4 with branchless masking: 4 independent row-gathers in flight.

__device__ __forceinline__ float bf16lo(unsigned u) { return __uint_as_float(u << 16); }
__device__ __forceinline__ float bf16hi(unsigned u) { return __uint_as_float(u & 0xffff0000u); }

__global__ __launch_bounds__(256) void agg_kernel(const unsigned* __restrict__ hwb,
                                                  const unsigned* __restrict__ row_ofs,
                                                  const uint2* __restrict__ edges,
                                                  const float* __restrict__ dinv, const float* __restrict__ bias,
                                                  float* __restrict__ out) {
  const int node = (blockIdx.x * 256 + threadIdx.x) >> 6;
  const int lane = threadIdx.x & 63;
  if (node >= NNODES) return;
  const unsigned ro = row_ofs[node], re = row_ofs[node + 1];
  const float di = dinv[node];
  const float w0 = di * di;
  unsigned u = hwb[(size_t)node * 64 + lane];          // self-loop row
  float acc0 = bf16lo(u) * w0;
  float acc1 = bf16hi(u) * w0;
  for (unsigned e = ro; e < re; e += 4) {
    // edges[] is padded by 4 records, so reading e..e+3 is always in-bounds memory.
    uint2 p0 = edges[e];
    uint2 p1 = edges[e + 1];
    uint2 p2 = edges[e + 2];
    uint2 p3 = edges[e + 3];
    const bool m1 = (e + 1 < re), m2 = (e + 2 < re), m3 = (e + 3 < re);
    const unsigned s0 = p0.x;
    const unsigned s1 = m1 ? p1.x : 0u;
    const unsigned s2 = m2 ? p2.x : 0u;
    const unsigned s3 = m3 ? p3.x : 0u;
    const float w0e = __uint_as_float(p0.y);
    const float w1e = m1 ? __uint_as_float(p1.y) : 0.f;
    const float w2e = m2 ? __uint_as_float(p2.y) : 0.f;
    const float w3e = m3 ? __uint_as_float(p3.y) : 0.f;
    const unsigned v0 = hwb[(size_t)s0 * 64 + lane];
    const unsigned v1 = hwb[(size_t)s1 * 64 + lane];
    const unsigned v2 = hwb[(size_t)s2 * 64 + lane];
    const unsigned v3 = hwb[(size_t)s3 * 64 + lane];
    acc0 = fmaf(bf16lo(v0), w0e, acc0);
    acc1 = fmaf(bf16hi(v0), w0e, acc1);
    acc0 = fmaf(bf16lo(v1), w1e, acc0);
    acc1 = fmaf(bf16hi(v1), w1e, acc1);
    acc0 = fmaf(bf16lo(v2), w2e, acc0);
    acc1 = fmaf(bf16hi(v2), w2e, acc1);
    acc0 = fmaf(bf16lo(v3), w3e, acc0);
    acc1 = fmaf(bf16hi(v3), w3e, acc1);
  }
  float2 o = make_float2(acc0 + bias[2 * lane], acc1 + bias[2 * lane + 1]);
  *reinterpret_cast<float2*>(&out[(size_t)node * HID + 2 * lane]) = o;
}

// ============================ BatchNorm stats ============================

__global__ __launch_bounds__(256) void stats_kernel(const float* __restrict__ h, float* __restrict__ stats) {
  float sum = 0.f, ssq = 0.f;
  const size_t total = (size_t)NNODES * HID;
  for (size_t i = (size_t)blockIdx.x * 256 + threadIdx.x; i < total; i += (size_t)gridDim.x * 256) {
    float v = h[i];
    sum += v; ssq += v * v;
  }
  __shared__ float s1[256], s2[256];
  s1[threadIdx.x] = sum; s2[threadIdx.x] = ssq;
  __syncthreads();
  if (threadIdx.x < 128) {
    int col = threadIdx.x;   // (blk*256+tid) % 128 == tid % 128 since strides are multiples of 128
    atomicAdd(&stats[col],       s1[threadIdx.x] + s1[threadIdx.x + 128]);
    atomicAdd(&stats[128 + col], s2[threadIdx.x] + s2[threadIdx.x + 128]);
  }
}

__global__ void finalize_kernel(const float* __restrict__ stats, const float* __restrict__ gamma,
                                const float* __restrict__ beta, float* __restrict__ ss, float inv_n) {
  int c = threadIdx.x;  // 128 threads
  float mu  = stats[c] * inv_n;
  float var = stats[128 + c] * inv_n - mu * mu;
  float scale = gamma[c] * rsqrtf(var + 1e-5f);
  ss[c]       = scale;
  ss[128 + c] = fmaf(-mu, scale, beta[c]);
}

__global__ __launch_bounds__(256) void normout_kernel(const float* __restrict__ h, const float* __restrict__ ss,
                                                      float* __restrict__ out) {
  size_t i = (size_t)blockIdx.x * 256 + threadIdx.x;
  if (i >= (size_t)NNODES * HID / 4) return;
  float4 v = reinterpret_cast<const float4*>(h)[i];
  int c = ((int)i & 31) * 4;
  v.x = fmaf(v.x, ss[c + 0], ss[128 + c + 0]);
  v.y = fmaf(v.y, ss[c + 1], ss[128 + c + 1]);
  v.z = fmaf(v.z, ss[c + 2], ss[128 + c + 2]);
  v.w = fmaf(v.w, ss[c + 3], ss[128 + c + 3]);
  reinterpret_cast<float4*>(out)[i] = v;
}

// ============================ launch ============================

extern "C" void kernel_launch(void* const* d_in, const int* in_sizes, int n_in,
                              void* d_out, int out_size, void* d_ws, size_t ws_size,
                              hipStream_t stream) {
  const float* x     = (const float*)d_in[0];
  const int*   ei    = (const int*)d_in[1];
  const float* ew    = (const float*)d_in[2];
  const float* W_in  = (const float*)d_in[3];
  const float* b_in  = (const float*)d_in[4];
  const float* W_mid = (const float*)d_in[5];
  const float* b_mid = (const float*)d_in[6];
  const float* W_out = (const float*)d_in[7];
  const float* b_out = (const float*)d_in[8];
  const float* gamma = (const float*)d_in[9];
  const float* beta  = (const float*)d_in[10];

  char* p = (char*)d_ws;
  auto alloc = [&](size_t bytes) -> char* {
    char* r = p;
    p += (bytes + 255) & ~(size_t)255;
    return r;
  };
  float*    wdeg    = (float*)alloc((size_t)NNODES * 4);
  unsigned* counts  = (unsigned*)alloc((size_t)NNODES * 4);
  float*    stats   = (float*)alloc(5 * 256 * 4);
  size_t zbytes = (size_t)(p - (char*)d_ws);          // wdeg+counts+stats get zeroed
  float*    dinv    = (float*)alloc((size_t)NNODES * 4);
  unsigned* row_ofs = (unsigned*)alloc((size_t)(NNODES + 1) * 4);
  unsigned* cursor  = (unsigned*)alloc((size_t)NNODES * 4);
  float*    ss      = (float*)alloc(5 * 256 * 4);
  unsigned* bsums   = (unsigned*)alloc(512 * 4);
  uint2*    edges   = (uint2*)alloc((size_t)(NEDGES + 4) * 8);  // +4 records: agg over-read pad
  float*    hA      = (float*)alloc((size_t)NNODES * HID * 4);
  float*    hB      = (float*)alloc((size_t)NNODES * HID * 4);
  unsigned* hw      = (unsigned*)d_out;               // reuse d_out as bf16x2 GEMM-output scratch (25.6MB of 51.2MB)

  hipMemsetAsync(d_ws, 0, zbytes, stream);

  const int eb = (NEDGES + 255) / 256;
  const int nb = (NNODES + 255) / 256;
  hist_kernel<<<eb, 256, 0, stream>>>(ei, ew, counts, wdeg);
  dinv_kernel<<<nb, 256, 0, stream>>>(wdeg, dinv);
  scan1_kernel<<<nb, 256, 0, stream>>>(counts, row_ofs, bsums);
  scan2_kernel<<<1, 512, 0, stream>>>(bsums, row_ofs, nb);
  scan3_kernel<<<nb, 256, 0, stream>>>(row_ofs, bsums, cursor);
  scatter_kernel<<<eb, 256, 0, stream>>>(ei, ew, dinv, cursor, edges);

  const int gb = (NNODES + 63) / 64;
  const int ab = (NNODES * 64 + 255) / 256;
  const float inv_n = 1.0f / NNODES;

  // layer 0: raw x (K=64), no BN on input
  gemm_kernel<INDIM, false><<<gb, 256, 0, stream>>>(x, W_in, nullptr, hw);
  agg_kernel<<<ab, 256, 0, stream>>>(hw, row_ofs, edges, dinv, b_in, hA);
  stats_kernel<<<512, 256, 0, stream>>>(hA, stats);
  finalize_kernel<<<1, 128, 0, stream>>>(stats, gamma, beta, ss, inv_n);

  const float* hin = hA;
  float* hout = hB;
  for (int l = 1; l <= 4; l++) {
    const float* W = (l <= 3) ? (W_mid + (size_t)(l - 1) * HID * HID) : W_out;
    const float* b = (l <= 3) ? (b_mid + (size_t)(l - 1) * HID) : b_out;
    gemm_kernel<HID, true><<<gb, 256, 0, stream>>>(hin, W, ss + (size_t)(l - 1) * 256, hw);
    agg_kernel<<<ab, 256, 0, stream>>>(hw, row_ofs, edges, dinv, b, hout);
    stats_kernel<<<512, 256, 0, stream>>>(hout, stats + (size_t)l * 256);
    finalize_kernel<<<1, 128, 0, stream>>>(stats + (size_t)l * 256, gamma + (size_t)l * HID,
                                           beta + (size_t)l * HID, ss + (size_t)l * 256, inv_n);
    const float* t = hout; hout = (float*)hin; hin = t;
  }
  // hin == layer-4 raw output; apply final BN (no ReLU) into d_out
  normout_kernel<<<((NNODES * HID / 4) + 255) / 256, 256, 0, stream>>>(hin, ss + 4 * 256, (float*)d_out);
}

// Round 4
// 864.912 us; speedup vs baseline: 1.8180x; 1.2415x over previous
//
#include <hip/hip_runtime.h>

#define NNODES 100000
#define NEDGES 1600000
#define HID    128
#define INDIM  64

typedef __attribute__((ext_vector_type(8))) short bf16x8;
typedef __attribute__((ext_vector_type(4))) float f32x4;

__device__ __forceinline__ unsigned pack_bf16x2(float a, float b) {
  unsigned ua = __float_as_uint(a), ub = __float_as_uint(b);
  ua = (ua + 0x7fffu + ((ua >> 16) & 1u)) >> 16;
  ub = (ub + 0x7fffu + ((ub >> 16) & 1u)) >> 16;
  return ua | (ub << 16);
}
__device__ __forceinline__ unsigned short bf16r(float x) {
  unsigned u = __float_as_uint(x);
  u = (u + 0x7fffu + ((u >> 16) & 1u)) >> 16;
  return (unsigned short)u;
}

// ============================ graph preprocessing ============================
// Packed histogram: one u64 atomic per edge. count in bits [63:40], wdeg Q8.24 in [39:0].

__global__ __launch_bounds__(256) void hist_kernel(const int* __restrict__ ei, const float* __restrict__ ew,
                                                   unsigned long long* __restrict__ packed) {
  int e = blockIdx.x * 256 + threadIdx.x;
  if (e >= NEDGES) return;
  int d = ei[NEDGES + e];
  unsigned long long inc = (1ULL << 40) | (unsigned long long)(ew[e] * 16777216.0f + 0.5f);
  atomicAdd(&packed[d], inc);
}

__global__ __launch_bounds__(256) void degcnt_kernel(const unsigned long long* __restrict__ packed,
                                                     unsigned* __restrict__ counts, float* __restrict__ dinv) {
  int i = blockIdx.x * 256 + threadIdx.x;
  if (i >= NNODES) return;
  unsigned long long r = packed[i];
  counts[i] = (unsigned)(r >> 40);
  float wd = (float)(r & 0xFFFFFFFFFFULL) * (1.0f / 16777216.0f);
  dinv[i] = rsqrtf(wd + 1.0f);
}

__global__ __launch_bounds__(256) void scan1_kernel(const unsigned* __restrict__ counts,
                                                    unsigned* __restrict__ part, unsigned* __restrict__ bsums) {
  __shared__ unsigned s[256];
  int i = blockIdx.x * 256 + threadIdx.x;
  unsigned v = (i < NNODES) ? counts[i] : 0u;
  s[threadIdx.x] = v;
  __syncthreads();
  for (int off = 1; off < 256; off <<= 1) {
    unsigned t = (threadIdx.x >= off) ? s[threadIdx.x - off] : 0u;
    __syncthreads();
    s[threadIdx.x] += t;
    __syncthreads();
  }
  if (i < NNODES) part[i] = s[threadIdx.x] - v;   // exclusive within block
  if (threadIdx.x == 255) bsums[blockIdx.x] = s[255];
}

__global__ void scan2_kernel(unsigned* __restrict__ bsums, unsigned* __restrict__ row_ofs, int nb) {
  __shared__ unsigned s[512];
  unsigned v = ((int)threadIdx.x < nb) ? bsums[threadIdx.x] : 0u;
  s[threadIdx.x] = v;
  __syncthreads();
  for (int off = 1; off < 512; off <<= 1) {
    unsigned t = (threadIdx.x >= off) ? s[threadIdx.x - off] : 0u;
    __syncthreads();
    s[threadIdx.x] += t;
    __syncthreads();
  }
  if ((int)threadIdx.x < nb) bsums[threadIdx.x] = s[threadIdx.x] - v; // exclusive block offsets
  if (threadIdx.x == 511) row_ofs[NNODES] = s[511];                   // total edge count
}

__global__ __launch_bounds__(256) void scan3_kernel(unsigned* __restrict__ row_ofs,
                                                    const unsigned* __restrict__ bsums,
                                                    unsigned* __restrict__ cursor) {
  int i = blockIdx.x * 256 + threadIdx.x;
  if (i < NNODES) {
    unsigned v = row_ofs[i] + bsums[blockIdx.x];
    row_ofs[i] = v;
    cursor[i] = v;
  }
}

// edges[pos] = {src, float_bits(norm)} — one 8B record per edge, interleaved for the agg gather.
__global__ __launch_bounds__(256) void scatter_kernel(const int* __restrict__ ei, const float* __restrict__ ew,
                                                      const float* __restrict__ dinv, unsigned* __restrict__ cursor,
                                                      uint2* __restrict__ edges) {
  int e = blockIdx.x * 256 + threadIdx.x;
  if (e >= NEDGES) return;
  int s = ei[e];
  int d = ei[NEDGES + e];
  unsigned pos = atomicAdd(&cursor[d], 1u);
  uint2 rec;
  rec.x = (unsigned)s;
  rec.y = __float_as_uint(ew[e] * dinv[s] * dinv[d]);
  edges[pos] = rec;
}

// ============================ W prep: transpose + bf16 ============================
// Wt[c][k] (bf16, padded stride KP) = W[k][c]; pads written zero.

template <int K, int KP>
__global__ __launch_bounds__(256) void wtprep_kernel(const float* __restrict__ W, unsigned short* __restrict__ Wt) {
  int idx = blockIdx.x * 256 + threadIdx.x;
  if (idx >= HID * KP) return;
  int c = idx / KP, k = idx % KP;
  unsigned short v = 0;
  if (k < K) v = bf16r(W[(size_t)k * HID + c]);
  Wt[idx] = v;
}

// ============================ GEMM (bf16 MFMA, bf16 output) ============================
// out[N,128](bf16) = f(A)[N,K] @ W[K,128]; f = BN(scale,shift)+ReLU if BN.
// Block: 256 thr = 4 waves, 64 rows. Wave w: rows [w*16, w*16+16), 8 col-frags, K/32 MFMA steps.

template <int K, bool BN>
__global__ __launch_bounds__(256) void gemm_kernel(const float* __restrict__ A,
                                                   const unsigned short* __restrict__ Wt,
                                                   const float* __restrict__ ss,
                                                   unsigned short* __restrict__ out) {
  constexpr int KP = (K == 128) ? 136 : 72;
  __shared__ unsigned short sW[HID * KP];
  __shared__ unsigned short sA[64 * KP];
  __shared__ float sScale[128];
  __shared__ float sShift[128];
  const int tid = threadIdx.x;
  if (BN && tid < K) { sScale[tid] = ss[tid]; sShift[tid] = ss[128 + tid]; }

  // Wt -> LDS (linear, uint4)
  {
    const uint4* g = (const uint4*)Wt;
    uint4* s = (uint4*)sW;
    const int n = HID * KP / 8;
    for (int i = tid; i < n; i += 256) s[i] = g[i];
  }

  // A panel -> BN/ReLU -> bf16 -> LDS
  const int row0 = blockIdx.x * 64;
  constexpr int TPR = K / 4;          // threads per row
  constexpr int RPP = 256 / TPR;      // rows per pass
  const int ar = tid / TPR;
  const int ak = (tid % TPR) * 4;
#pragma unroll
  for (int rp = 0; rp < 64; rp += RPP) {
    int row = rp + ar;
    int grow = row0 + row;
    float4 v = make_float4(0.f, 0.f, 0.f, 0.f);
    if (grow < NNODES) v = *reinterpret_cast<const float4*>(&A[(size_t)grow * K + ak]);
    if (BN) {
      v.x = fmaxf(fmaf(v.x, sScale[ak + 0], sShift[ak + 0]), 0.f);
      v.y = fmaxf(fmaf(v.y, sScale[ak + 1], sShift[ak + 1]), 0.f);
      v.z = fmaxf(fmaf(v.z, sScale[ak + 2], sShift[ak + 2]), 0.f);
      v.w = fmaxf(fmaf(v.w, sScale[ak + 3], sShift[ak + 3]), 0.f);
    }
    uint2 pk = make_uint2(pack_bf16x2(v.x, v.y), pack_bf16x2(v.z, v.w));
    *reinterpret_cast<uint2*>(&sA[row * KP + ak]) = pk;
  }
  __syncthreads();

  const int wid = tid >> 6;
  const int lane = tid & 63;
  const int wrow = wid * 16;
  const int fr = lane & 15;
  const int fk = (lane >> 4) * 8;

  f32x4 acc[8];
#pragma unroll
  for (int cf = 0; cf < 8; cf++) acc[cf] = (f32x4){0.f, 0.f, 0.f, 0.f};

  bf16x8 afrag[K / 32];
#pragma unroll
  for (int ks = 0; ks < K / 32; ks++)
    afrag[ks] = *reinterpret_cast<const bf16x8*>(&sA[(wrow + fr) * KP + ks * 32 + fk]);

#pragma unroll
  for (int cf = 0; cf < 8; cf++) {
#pragma unroll
    for (int ks = 0; ks < K / 32; ks++) {
      bf16x8 b = *reinterpret_cast<const bf16x8*>(&sW[(cf * 16 + fr) * KP + ks * 32 + fk]);
      acc[cf] = __builtin_amdgcn_mfma_f32_16x16x32_bf16(afrag[ks], b, acc[cf], 0, 0, 0);
    }
  }

  // D: col = cf*16 + (lane&15), row = wrow + (lane>>4)*4 + j
  const int orow = (lane >> 4) * 4;
#pragma unroll
  for (int cf = 0; cf < 8; cf++) {
    const int col = cf * 16 + fr;
#pragma unroll
    for (int j = 0; j < 4; j++) {
      int grow = row0 + wrow + orow + j;
      if (grow < NNODES) out[(size_t)grow * HID + col] = bf16r(acc[cf][j]);
    }
  }
}

// ============================ aggregation (CSR gather, bf16 rows, 4-deep MLP) ============================

__device__ __forceinline__ float bf16lo(unsigned u) { return __uint_as_float(u << 16); }
__device__ __forceinline__ float bf16hi(unsigned u) { return __uint_as_float(u & 0xffff0000u); }

__global__ __launch_bounds__(256) void agg_kernel(const unsigned* __restrict__ hwb,
                                                  const unsigned* __restrict__ row_ofs,
                                                  const uint2* __restrict__ edges,
                                                  const float* __restrict__ dinv, const float* __restrict__ bias,
                                                  float* __restrict__ out) {
  const int node = (blockIdx.x * 256 + threadIdx.x) >> 6;
  const int lane = threadIdx.x & 63;
  if (node >= NNODES) return;
  const unsigned ro = row_ofs[node], re = row_ofs[node + 1];
  const float di = dinv[node];
  const float w0 = di * di;
  unsigned u = hwb[(size_t)node * 64 + lane];          // self-loop row
  float acc0 = bf16lo(u) * w0;
  float acc1 = bf16hi(u) * w0;
  for (unsigned e = ro; e < re; e += 4) {
    // edges[] is padded by 4 records, so reading e..e+3 is always in-bounds memory.
    uint2 p0 = edges[e];
    uint2 p1 = edges[e + 1];
    uint2 p2 = edges[e + 2];
    uint2 p3 = edges[e + 3];
    const bool m1 = (e + 1 < re), m2 = (e + 2 < re), m3 = (e + 3 < re);
    const unsigned s0 = p0.x;
    const unsigned s1 = m1 ? p1.x : 0u;
    const unsigned s2 = m2 ? p2.x : 0u;
    const unsigned s3 = m3 ? p3.x : 0u;
    const float w0e = __uint_as_float(p0.y);
    const float w1e = m1 ? __uint_as_float(p1.y) : 0.f;
    const float w2e = m2 ? __uint_as_float(p2.y) : 0.f;
    const float w3e = m3 ? __uint_as_float(p3.y) : 0.f;
    const unsigned v0 = hwb[(size_t)s0 * 64 + lane];
    const unsigned v1 = hwb[(size_t)s1 * 64 + lane];
    const unsigned v2 = hwb[(size_t)s2 * 64 + lane];
    const unsigned v3 = hwb[(size_t)s3 * 64 + lane];
    acc0 = fmaf(bf16lo(v0), w0e, acc0);
    acc1 = fmaf(bf16hi(v0), w0e, acc1);
    acc0 = fmaf(bf16lo(v1), w1e, acc0);
    acc1 = fmaf(bf16hi(v1), w1e, acc1);
    acc0 = fmaf(bf16lo(v2), w2e, acc0);
    acc1 = fmaf(bf16hi(v2), w2e, acc1);
    acc0 = fmaf(bf16lo(v3), w3e, acc0);
    acc1 = fmaf(bf16hi(v3), w3e, acc1);
  }
  float2 o = make_float2(acc0 + bias[2 * lane], acc1 + bias[2 * lane + 1]);
  *reinterpret_cast<float2*>(&out[(size_t)node * HID + 2 * lane]) = o;
}

// ============================ BatchNorm stats ============================

__global__ __launch_bounds__(256) void stats_kernel(const float* __restrict__ h, float* __restrict__ stats) {
  float sum = 0.f, ssq = 0.f;
  const size_t total = (size_t)NNODES * HID;
  for (size_t i = (size_t)blockIdx.x * 256 + threadIdx.x; i < total; i += (size_t)gridDim.x * 256) {
    float v = h[i];
    sum += v; ssq += v * v;
  }
  __shared__ float s1[256], s2[256];
  s1[threadIdx.x] = sum; s2[threadIdx.x] = ssq;
  __syncthreads();
  if (threadIdx.x < 128) {
    int col = threadIdx.x;   // (blk*256+tid) % 128 == tid % 128 since strides are multiples of 128
    atomicAdd(&stats[col],       s1[threadIdx.x] + s1[threadIdx.x + 128]);
    atomicAdd(&stats[128 + col], s2[threadIdx.x] + s2[threadIdx.x + 128]);
  }
}

__global__ void finalize_kernel(const float* __restrict__ stats, const float* __restrict__ gamma,
                                const float* __restrict__ beta, float* __restrict__ ss, float inv_n) {
  int c = threadIdx.x;  // 128 threads
  float mu  = stats[c] * inv_n;
  float var = stats[128 + c] * inv_n - mu * mu;
  float scale = gamma[c] * rsqrtf(var + 1e-5f);
  ss[c]       = scale;
  ss[128 + c] = fmaf(-mu, scale, beta[c]);
}

__global__ __launch_bounds__(256) void normout_kernel(const float* __restrict__ h, const float* __restrict__ ss,
                                                      float* __restrict__ out) {
  size_t i = (size_t)blockIdx.x * 256 + threadIdx.x;
  if (i >= (size_t)NNODES * HID / 4) return;
  float4 v = reinterpret_cast<const float4*>(h)[i];
  int c = ((int)i & 31) * 4;
  v.x = fmaf(v.x, ss[c + 0], ss[128 + c + 0]);
  v.y = fmaf(v.y, ss[c + 1], ss[128 + c + 1]);
  v.z = fmaf(v.z, ss[c + 2], ss[128 + c + 2]);
  v.w = fmaf(v.w, ss[c + 3], ss[128 + c + 3]);
  reinterpret_cast<float4*>(out)[i] = v;
}

// ============================ launch ============================

extern "C" void kernel_launch(void* const* d_in, const int* in_sizes, int n_in,
                              void* d_out, int out_size, void* d_ws, size_t ws_size,
                              hipStream_t stream) {
  const float* x     = (const float*)d_in[0];
  const int*   ei    = (const int*)d_in[1];
  const float* ew    = (const float*)d_in[2];
  const float* W_in  = (const float*)d_in[3];
  const float* b_in  = (const float*)d_in[4];
  const float* W_mid = (const float*)d_in[5];
  const float* b_mid = (const float*)d_in[6];
  const float* W_out = (const float*)d_in[7];
  const float* b_out = (const float*)d_in[8];
  const float* gamma = (const float*)d_in[9];
  const float* beta  = (const float*)d_in[10];

  char* p = (char*)d_ws;
  auto alloc = [&](size_t bytes) -> char* {
    char* r = p;
    p += (bytes + 255) & ~(size_t)255;
    return r;
  };
  unsigned long long* packed = (unsigned long long*)alloc((size_t)NNODES * 8);
  float*    stats   = (float*)alloc(5 * 256 * 4);
  size_t zbytes = (size_t)(p - (char*)d_ws);          // packed + stats get zeroed
  unsigned* counts  = (unsigned*)alloc((size_t)NNODES * 4);
  float*    dinv    = (float*)alloc((size_t)NNODES * 4);
  unsigned* row_ofs = (unsigned*)alloc((size_t)(NNODES + 1) * 4);
  unsigned* cursor  = (unsigned*)alloc((size_t)NNODES * 4);
  float*    ss      = (float*)alloc(5 * 256 * 4);
  unsigned* bsums   = (unsigned*)alloc(512 * 4);
  uint2*    edges   = (uint2*)alloc((size_t)(NEDGES + 4) * 8);  // +4 records: agg over-read pad
  float*    hA      = (float*)alloc((size_t)NNODES * HID * 4);
  float*    hB      = (float*)alloc((size_t)NNODES * HID * 4);
  unsigned short* wt = (unsigned short*)alloc((size_t)HID * 136 * 2);
  unsigned short* hw = (unsigned short*)d_out;        // reuse d_out as bf16 GEMM-output scratch

  hipMemsetAsync(d_ws, 0, zbytes, stream);

  const int eb = (NEDGES + 255) / 256;
  const int nb = (NNODES + 255) / 256;
  hist_kernel<<<eb, 256, 0, stream>>>(ei, ew, packed);
  degcnt_kernel<<<nb, 256, 0, stream>>>(packed, counts, dinv);
  scan1_kernel<<<nb, 256, 0, stream>>>(counts, row_ofs, bsums);
  scan2_kernel<<<1, 512, 0, stream>>>(bsums, row_ofs, nb);
  scan3_kernel<<<nb, 256, 0, stream>>>(row_ofs, bsums, cursor);
  scatter_kernel<<<eb, 256, 0, stream>>>(ei, ew, dinv, cursor, edges);

  const int gb = (NNODES + 63) / 64;
  const int ab = (NNODES * 64 + 255) / 256;
  const float inv_n = 1.0f / NNODES;

  // layer 0: raw x (K=64), no BN on input
  wtprep_kernel<INDIM, 72><<<(HID * 72 + 255) / 256, 256, 0, stream>>>(W_in, wt);
  gemm_kernel<INDIM, false><<<gb, 256, 0, stream>>>(x, wt, nullptr, hw);
  agg_kernel<<<ab, 256, 0, stream>>>((const unsigned*)hw, row_ofs, edges, dinv, b_in, hA);
  stats_kernel<<<512, 256, 0, stream>>>(hA, stats);
  finalize_kernel<<<1, 128, 0, stream>>>(stats, gamma, beta, ss, inv_n);

  const float* hin = hA;
  float* hout = hB;
  for (int l = 1; l <= 4; l++) {
    const float* W = (l <= 3) ? (W_mid + (size_t)(l - 1) * HID * HID) : W_out;
    const float* b = (l <= 3) ? (b_mid + (size_t)(l - 1) * HID) : b_out;
    wtprep_kernel<HID, 136><<<(HID * 136 + 255) / 256, 256, 0, stream>>>(W, wt);
    gemm_kernel<HID, true><<<gb, 256, 0, stream>>>(hin, wt, ss + (size_t)(l - 1) * 256, hw);
    agg_kernel<<<ab, 256, 0, stream>>>((const unsigned*)hw, row_ofs, edges, dinv, b, hout);
    stats_kernel<<<512, 256, 0, stream>>>(hout, stats + (size_t)l * 256);
    finalize_kernel<<<1, 128, 0, stream>>>(stats + (size_t)l * 256, gamma + (size_t)l * HID,
                                           beta + (size_t)l * HID, ss + (size_t)l * 256, inv_n);
    const float* t = hout; hout = (float*)hin; hin = t;
  }
  // hin == layer-4 raw output; apply final BN (no ReLU) into d_out
  normout_kernel<<<((NNODES * HID / 4) + 255) / 256, 256, 0, stream>>>(hin, ss + 4 * 256, (float*)d_out);
}

// Round 5
// 745.639 us; speedup vs baseline: 2.1088x; 1.1600x over previous
//
#include <hip/hip_runtime.h>

#define NNODES 100000
#define NEDGES 1600000
#define HID    128
#define INDIM  64

typedef __attribute__((ext_vector_type(8))) short bf16x8;
typedef __attribute__((ext_vector_type(4))) float f32x4;

__device__ __forceinline__ unsigned pack_bf16x2(float a, float b) {
  unsigned ua = __float_as_uint(a), ub = __float_as_uint(b);
  ua = (ua + 0x7fffu + ((ua >> 16) & 1u)) >> 16;
  ub = (ub + 0x7fffu + ((ub >> 16) & 1u)) >> 16;
  return ua | (ub << 16);
}
__device__ __forceinline__ unsigned short bf16r(float x) {
  unsigned u = __float_as_uint(x);
  u = (u + 0x7fffu + ((u >> 16) & 1u)) >> 16;
  return (unsigned short)u;
}
__device__ __forceinline__ float bf16lo(unsigned u) { return __uint_as_float(u << 16); }
__device__ __forceinline__ float bf16hi(unsigned u) { return __uint_as_float(u & 0xffff0000u); }

// ============================ x -> bf16 ============================

__global__ __launch_bounds__(256) void xprep_kernel(const float* __restrict__ x, uint2* __restrict__ xb) {
  int idx = blockIdx.x * 256 + threadIdx.x;
  if (idx >= NNODES * INDIM / 4) return;
  float4 v = reinterpret_cast<const float4*>(x)[idx];
  xb[idx] = make_uint2(pack_bf16x2(v.x, v.y), pack_bf16x2(v.z, v.w));
}

// ============================ graph preprocessing ============================
// Packed histogram: one u64 atomic per edge; count in [63:40], wdeg Q8.24 in [39:0].
// The atomic's RETURN carries the edge's rank within its destination -> scatter needs no atomic.

__global__ __launch_bounds__(256) void hist_kernel(const int* __restrict__ ei, const float* __restrict__ ew,
                                                   unsigned long long* __restrict__ packed,
                                                   unsigned* __restrict__ rank) {
  int e = blockIdx.x * 256 + threadIdx.x;
  if (e >= NEDGES) return;
  int d = ei[NEDGES + e];
  unsigned long long inc = (1ULL << 40) | (unsigned long long)(ew[e] * 16777216.0f + 0.5f);
  unsigned long long old = atomicAdd(&packed[d], inc);
  rank[e] = (unsigned)(old >> 40);
}

__global__ __launch_bounds__(256) void degcnt_kernel(const unsigned long long* __restrict__ packed,
                                                     unsigned* __restrict__ counts, float* __restrict__ dinv) {
  int i = blockIdx.x * 256 + threadIdx.x;
  if (i >= NNODES) return;
  unsigned long long r = packed[i];
  counts[i] = (unsigned)(r >> 40);
  float wd = (float)(r & 0xFFFFFFFFFFULL) * (1.0f / 16777216.0f);
  dinv[i] = rsqrtf(wd + 1.0f);
}

__global__ __launch_bounds__(256) void scan1_kernel(const unsigned* __restrict__ counts,
                                                    unsigned* __restrict__ part, unsigned* __restrict__ bsums) {
  __shared__ unsigned s[256];
  int i = blockIdx.x * 256 + threadIdx.x;
  unsigned v = (i < NNODES) ? counts[i] : 0u;
  s[threadIdx.x] = v;
  __syncthreads();
  for (int off = 1; off < 256; off <<= 1) {
    unsigned t = (threadIdx.x >= off) ? s[threadIdx.x - off] : 0u;
    __syncthreads();
    s[threadIdx.x] += t;
    __syncthreads();
  }
  if (i < NNODES) part[i] = s[threadIdx.x] - v;
  if (threadIdx.x == 255) bsums[blockIdx.x] = s[255];
}

__global__ void scan2_kernel(unsigned* __restrict__ bsums, unsigned* __restrict__ row_ofs, int nb) {
  __shared__ unsigned s[512];
  unsigned v = ((int)threadIdx.x < nb) ? bsums[threadIdx.x] : 0u;
  s[threadIdx.x] = v;
  __syncthreads();
  for (int off = 1; off < 512; off <<= 1) {
    unsigned t = (threadIdx.x >= off) ? s[threadIdx.x - off] : 0u;
    __syncthreads();
    s[threadIdx.x] += t;
    __syncthreads();
  }
  if ((int)threadIdx.x < nb) bsums[threadIdx.x] = s[threadIdx.x] - v;
  if (threadIdx.x == 511) row_ofs[NNODES] = s[511];
}

__global__ __launch_bounds__(256) void scan3_kernel(unsigned* __restrict__ row_ofs,
                                                    const unsigned* __restrict__ bsums) {
  int i = blockIdx.x * 256 + threadIdx.x;
  if (i < NNODES) row_ofs[i] += bsums[blockIdx.x];
}

// edges[pos] = {src, float_bits(norm)}; pos = row_ofs[d] + rank[e] (atomic-free).
__global__ __launch_bounds__(256) void scatter_kernel(const int* __restrict__ ei, const float* __restrict__ ew,
                                                      const float* __restrict__ dinv,
                                                      const unsigned* __restrict__ rank,
                                                      const unsigned* __restrict__ row_ofs,
                                                      uint2* __restrict__ edges) {
  int e = blockIdx.x * 256 + threadIdx.x;
  if (e >= NEDGES) return;
  int s = ei[e];
  int d = ei[NEDGES + e];
  unsigned pos = row_ofs[d] + rank[e];
  uint2 rec;
  rec.x = (unsigned)s;
  rec.y = __float_as_uint(ew[e] * dinv[s] * dinv[d]);
  edges[pos] = rec;
}

// ============================ W prep: transpose + bf16 ============================

template <int K, int KP>
__global__ __launch_bounds__(256) void wtprep_kernel(const float* __restrict__ W, unsigned short* __restrict__ Wt) {
  int idx = blockIdx.x * 256 + threadIdx.x;
  if (idx >= HID * KP) return;
  int c = idx / KP, k = idx % KP;
  unsigned short v = 0;
  if (k < K) v = bf16r(W[(size_t)k * HID + c]);
  Wt[idx] = v;
}

// ============================ aggregation (CSR gather, bf16 rows, f(h) inline) ============================
// t = S · f(h): per gathered row apply BN(scale,shift)+ReLU (if BN) in fp32, weighted-sum, write bf16.
// LANES = uint32 words per row (2 cols each). One sub-wave of LANES lanes per node.

template <int LANES, bool BN>
__global__ __launch_bounds__(256) void agg_kernel(const unsigned* __restrict__ hb,
                                                  const unsigned* __restrict__ row_ofs,
                                                  const uint2* __restrict__ edges,
                                                  const float* __restrict__ dinv,
                                                  const float* __restrict__ ss,
                                                  unsigned* __restrict__ outb) {
  const int gid = blockIdx.x * 256 + threadIdx.x;
  const int node = gid / LANES;
  const int lane = gid % LANES;
  if (node >= NNODES) return;
  float s0 = 1.f, s1 = 1.f, t0 = 0.f, t1 = 0.f;
  if (BN) {
    float2 sc = reinterpret_cast<const float2*>(ss)[lane];
    float2 sh = reinterpret_cast<const float2*>(ss + 128)[lane];
    s0 = sc.x; s1 = sc.y; t0 = sh.x; t1 = sh.y;
  }
  const unsigned ro = row_ofs[node], re = row_ofs[node + 1];
  const float di = dinv[node];
  const float wself = di * di;
  unsigned u = hb[(size_t)node * LANES + lane];
  float a = bf16lo(u), b = bf16hi(u);
  if (BN) { a = fmaxf(fmaf(a, s0, t0), 0.f); b = fmaxf(fmaf(b, s1, t1), 0.f); }
  float acc0 = a * wself, acc1 = b * wself;
  for (unsigned e = ro; e < re; e += 4) {
    // edges[] padded by 4 records; lanes of masked slots get w=0, src=0.
    uint2 p0 = edges[e];
    uint2 p1 = edges[e + 1];
    uint2 p2 = edges[e + 2];
    uint2 p3 = edges[e + 3];
    const bool m1 = (e + 1 < re), m2 = (e + 2 < re), m3 = (e + 3 < re);
    const unsigned sx0 = p0.x;
    const unsigned sx1 = m1 ? p1.x : 0u;
    const unsigned sx2 = m2 ? p2.x : 0u;
    const unsigned sx3 = m3 ? p3.x : 0u;
    const float w0e = __uint_as_float(p0.y);
    const float w1e = m1 ? __uint_as_float(p1.y) : 0.f;
    const float w2e = m2 ? __uint_as_float(p2.y) : 0.f;
    const float w3e = m3 ? __uint_as_float(p3.y) : 0.f;
    const unsigned v0 = hb[(size_t)sx0 * LANES + lane];
    const unsigned v1 = hb[(size_t)sx1 * LANES + lane];
    const unsigned v2 = hb[(size_t)sx2 * LANES + lane];
    const unsigned v3 = hb[(size_t)sx3 * LANES + lane];
    float a0 = bf16lo(v0), b0 = bf16hi(v0);
    float a1 = bf16lo(v1), b1 = bf16hi(v1);
    float a2 = bf16lo(v2), b2 = bf16hi(v2);
    float a3 = bf16lo(v3), b3 = bf16hi(v3);
    if (BN) {
      a0 = fmaxf(fmaf(a0, s0, t0), 0.f); b0 = fmaxf(fmaf(b0, s1, t1), 0.f);
      a1 = fmaxf(fmaf(a1, s0, t0), 0.f); b1 = fmaxf(fmaf(b1, s1, t1), 0.f);
      a2 = fmaxf(fmaf(a2, s0, t0), 0.f); b2 = fmaxf(fmaf(b2, s1, t1), 0.f);
      a3 = fmaxf(fmaf(a3, s0, t0), 0.f); b3 = fmaxf(fmaf(b3, s1, t1), 0.f);
    }
    acc0 = fmaf(a0, w0e, acc0); acc1 = fmaf(b0, w0e, acc1);
    acc0 = fmaf(a1, w1e, acc0); acc1 = fmaf(b1, w1e, acc1);
    acc0 = fmaf(a2, w2e, acc0); acc1 = fmaf(b2, w2e, acc1);
    acc0 = fmaf(a3, w3e, acc0); acc1 = fmaf(b3, w3e, acc1);
  }
  outb[(size_t)node * LANES + lane] = pack_bf16x2(acc0, acc1);
}

// ============================ GEMM (bf16 MFMA): h = t @ W + b ============================

template <int K>
__global__ __launch_bounds__(256) void gemm_kernel(const unsigned short* __restrict__ A,   // bf16 [N,K]
                                                   const unsigned short* __restrict__ Wt,  // bf16 [HID,KP]
                                                   const float* __restrict__ bias,
                                                   unsigned short* __restrict__ out) {     // bf16 [N,HID]
  constexpr int KP = (K == 128) ? 136 : 72;
  __shared__ __align__(16) unsigned short sW[HID * KP];
  __shared__ __align__(16) unsigned short sA[64 * KP];
  const int tid = threadIdx.x;

  // Wt -> LDS (linear uint4)
  {
    const uint4* g = (const uint4*)Wt;
    uint4* s = (uint4*)sW;
    const int n = HID * KP / 8;
    for (int i = tid; i < n; i += 256) s[i] = g[i];
  }

  // A panel (already bf16) -> LDS
  const int row0 = blockIdx.x * 64;
  constexpr int CPR = K / 8;      // uint4 chunks per row
  const uint4* Ag = (const uint4*)A;
#pragma unroll
  for (int i = tid; i < 64 * CPR; i += 256) {
    int row = i / CPR, ch = i % CPR;
    int grow = row0 + row;
    uint4 v = make_uint4(0u, 0u, 0u, 0u);
    if (grow < NNODES) v = Ag[(size_t)grow * CPR + ch];
    *reinterpret_cast<uint4*>(&sA[row * KP + ch * 8]) = v;
  }
  __syncthreads();

  const int wid = tid >> 6;
  const int lane = tid & 63;
  const int wrow = wid * 16;
  const int fr = lane & 15;
  const int fk = (lane >> 4) * 8;

  f32x4 acc[8];
#pragma unroll
  for (int cf = 0; cf < 8; cf++) acc[cf] = (f32x4){0.f, 0.f, 0.f, 0.f};

  bf16x8 afrag[K / 32];
#pragma unroll
  for (int ks = 0; ks < K / 32; ks++)
    afrag[ks] = *reinterpret_cast<const bf16x8*>(&sA[(wrow + fr) * KP + ks * 32 + fk]);

#pragma unroll
  for (int cf = 0; cf < 8; cf++) {
#pragma unroll
    for (int ks = 0; ks < K / 32; ks++) {
      bf16x8 b = *reinterpret_cast<const bf16x8*>(&sW[(cf * 16 + fr) * KP + ks * 32 + fk]);
      acc[cf] = __builtin_amdgcn_mfma_f32_16x16x32_bf16(afrag[ks], b, acc[cf], 0, 0, 0);
    }
  }

  const int orow = (lane >> 4) * 4;
#pragma unroll
  for (int cf = 0; cf < 8; cf++) {
    const int col = cf * 16 + fr;
    const float bv = bias[col];
#pragma unroll
    for (int j = 0; j < 4; j++) {
      int grow = row0 + wrow + orow + j;
      if (grow < NNODES) out[(size_t)grow * HID + col] = bf16r(acc[cf][j] + bv);
    }
  }
}

// ============================ BatchNorm stats (bf16 input) ============================

__global__ __launch_bounds__(256) void stats_kernel(const uint4* __restrict__ hb, float* __restrict__ stats) {
  __shared__ float sS[128], sQ[128];
  if (threadIdx.x < 128) { sS[threadIdx.x] = 0.f; sQ[threadIdx.x] = 0.f; }
  __syncthreads();
  float s[8] = {}, q[8] = {};
  const int total = NNODES * 16;          // uint4 = 8 bf16
  for (int i = blockIdx.x * 256 + threadIdx.x; i < total; i += gridDim.x * 256) {
    uint4 v = hb[i];
    float x0 = bf16lo(v.x), x1 = bf16hi(v.x), x2 = bf16lo(v.y), x3 = bf16hi(v.y);
    float x4 = bf16lo(v.z), x5 = bf16hi(v.z), x6 = bf16lo(v.w), x7 = bf16hi(v.w);
    s[0] += x0; q[0] += x0 * x0;  s[1] += x1; q[1] += x1 * x1;
    s[2] += x2; q[2] += x2 * x2;  s[3] += x3; q[3] += x3 * x3;
    s[4] += x4; q[4] += x4 * x4;  s[5] += x5; q[5] += x5 * x5;
    s[6] += x6; q[6] += x6 * x6;  s[7] += x7; q[7] += x7 * x7;
  }
  const int cb = (threadIdx.x & 15) * 8;  // (i*8)%128 == ((tid%16)*8) since strides are x16
#pragma unroll
  for (int j = 0; j < 8; j++) {
    atomicAdd(&sS[cb + j], s[j]);
    atomicAdd(&sQ[cb + j], q[j]);
  }
  __syncthreads();
  if (threadIdx.x < 128) {
    atomicAdd(&stats[threadIdx.x],       sS[threadIdx.x]);
    atomicAdd(&stats[128 + threadIdx.x], sQ[threadIdx.x]);
  }
}

__global__ void finalize_kernel(const float* __restrict__ stats, const float* __restrict__ gamma,
                                const float* __restrict__ beta, float* __restrict__ ss, float inv_n) {
  int c = threadIdx.x;  // 128
  float mu  = stats[c] * inv_n;
  float var = stats[128 + c] * inv_n - mu * mu;
  float scale = gamma[c] * rsqrtf(var + 1e-5f);
  ss[c]       = scale;
  ss[128 + c] = fmaf(-mu, scale, beta[c]);
}

// final: out(fp32) = BN(h4), no ReLU
__global__ __launch_bounds__(256) void normout_kernel(const unsigned* __restrict__ hb,
                                                      const float* __restrict__ ss, float2* __restrict__ out) {
  int idx = blockIdx.x * 256 + threadIdx.x;
  if (idx >= NNODES * 64) return;
  unsigned u = hb[idx];
  int c = (idx & 63) * 2;
  out[idx] = make_float2(fmaf(bf16lo(u), ss[c],     ss[128 + c]),
                         fmaf(bf16hi(u), ss[c + 1], ss[128 + c + 1]));
}

// ============================ launch ============================

extern "C" void kernel_launch(void* const* d_in, const int* in_sizes, int n_in,
                              void* d_out, int out_size, void* d_ws, size_t ws_size,
                              hipStream_t stream) {
  const float* x     = (const float*)d_in[0];
  const int*   ei    = (const int*)d_in[1];
  const float* ew    = (const float*)d_in[2];
  const float* W_in  = (const float*)d_in[3];
  const float* b_in  = (const float*)d_in[4];
  const float* W_mid = (const float*)d_in[5];
  const float* b_mid = (const float*)d_in[6];
  const float* W_out = (const float*)d_in[7];
  const float* b_out = (const float*)d_in[8];
  const float* gamma = (const float*)d_in[9];
  const float* beta  = (const float*)d_in[10];

  char* p = (char*)d_ws;
  auto alloc = [&](size_t bytes) -> char* {
    char* r = p;
    p += (bytes + 255) & ~(size_t)255;
    return r;
  };
  unsigned long long* packed = (unsigned long long*)alloc((size_t)NNODES * 8);
  float*    stats   = (float*)alloc(5 * 256 * 4);
  size_t zbytes = (size_t)(p - (char*)d_ws);          // packed + stats get zeroed
  unsigned* counts  = (unsigned*)alloc((size_t)NNODES * 4);
  float*    dinv    = (float*)alloc((size_t)NNODES * 4);
  unsigned* row_ofs = (unsigned*)alloc((size_t)(NNODES + 1) * 4);
  unsigned* bsums   = (unsigned*)alloc(512 * 4);
  float*    ss      = (float*)alloc(5 * 256 * 4);
  unsigned* rank    = (unsigned*)alloc((size_t)NEDGES * 4);
  uint2*    edges   = (uint2*)alloc((size_t)(NEDGES + 4) * 8);
  unsigned* xb      = (unsigned*)alloc((size_t)NNODES * INDIM * 2);
  unsigned short* h = (unsigned short*)alloc((size_t)NNODES * HID * 2);
  unsigned short* t = (unsigned short*)alloc((size_t)NNODES * HID * 2);
  unsigned short* wt = (unsigned short*)alloc((size_t)HID * 136 * 2);

  hipMemsetAsync(d_ws, 0, zbytes, stream);

  const int eb = (NEDGES + 255) / 256;
  const int nb = (NNODES + 255) / 256;
  const int gb = (NNODES + 63) / 64;
  const float inv_n = 1.0f / NNODES;

  xprep_kernel<<<(NNODES * INDIM / 4 + 255) / 256, 256, 0, stream>>>(x, (uint2*)xb);
  hist_kernel<<<eb, 256, 0, stream>>>(ei, ew, packed, rank);
  degcnt_kernel<<<nb, 256, 0, stream>>>(packed, counts, dinv);
  scan1_kernel<<<nb, 256, 0, stream>>>(counts, row_ofs, bsums);
  scan2_kernel<<<1, 512, 0, stream>>>(bsums, row_ofs, nb);
  scan3_kernel<<<nb, 256, 0, stream>>>(row_ofs, bsums);
  scatter_kernel<<<eb, 256, 0, stream>>>(ei, ew, dinv, rank, row_ofs, edges);

  // layer 0: t0 = S·x (bf16, N x 64); h = t0 @ W_in + b_in
  agg_kernel<32, false><<<(NNODES * 32) / 256, 256, 0, stream>>>(xb, row_ofs, edges, dinv, nullptr, (unsigned*)t);
  wtprep_kernel<INDIM, 72><<<(HID * 72 + 255) / 256, 256, 0, stream>>>(W_in, wt);
  gemm_kernel<INDIM><<<gb, 256, 0, stream>>>((const unsigned short*)t, wt, b_in, h);

  // layers 1..4: stats(h) -> ss ; t = S·relu(bn(h)) ; h = t @ W_l + b_l
  for (int l = 1; l <= 4; l++) {
    stats_kernel<<<512, 256, 0, stream>>>((const uint4*)h, stats + (size_t)(l - 1) * 256);
    finalize_kernel<<<1, 128, 0, stream>>>(stats + (size_t)(l - 1) * 256, gamma + (size_t)(l - 1) * HID,
                                           beta + (size_t)(l - 1) * HID, ss + (size_t)(l - 1) * 256, inv_n);
    agg_kernel<64, true><<<(NNODES * 64) / 256, 256, 0, stream>>>((const unsigned*)h, row_ofs, edges, dinv,
                                                                  ss + (size_t)(l - 1) * 256, (unsigned*)t);
    const float* W = (l <= 3) ? (W_mid + (size_t)(l - 1) * HID * HID) : W_out;
    const float* b = (l <= 3) ? (b_mid + (size_t)(l - 1) * HID) : b_out;
    wtprep_kernel<HID, 136><<<(HID * 136 + 255) / 256, 256, 0, stream>>>(W, wt);
    gemm_kernel<HID><<<gb, 256, 0, stream>>>((const unsigned short*)t, wt, b, h);
  }

  // final BN (no ReLU) on h4 -> d_out (fp32)
  stats_kernel<<<512, 256, 0, stream>>>((const uint4*)h, stats + 4 * 256);
  finalize_kernel<<<1, 128, 0, stream>>>(stats + 4 * 256, gamma + 4 * HID, beta + 4 * HID, ss + 4 * 256, inv_n);
  normout_kernel<<<(NNODES * 64) / 256, 256, 0, stream>>>((const unsigned*)h, ss + 4 * 256, (float2*)d_out);
}